// Round 1
// baseline (540.912 us; speedup 1.0000x reference)
//
#include <hip/hip_runtime.h>
#include <hip/hip_bf16.h>
#include <math.h>

static constexpr float SP_BIAS = 0.5413248546129181f; // log(expm1(1.0))

// ---------------------------------------------------------------------------
// Kernel A: detect whether edge_index buffer is int32 or int64 layout.
// If int64 (values < 2^31), every odd int32 word (high half) is 0.
// flag = 0 -> int32 layout, flag = 1 -> int64 layout.
__global__ void k_detect(const int* __restrict__ ei32, int n_check,
                         int* __restrict__ flag) {
    __shared__ int any;
    if (threadIdx.x == 0) any = 0;
    __syncthreads();
    int found = 0;
    for (int i = threadIdx.x; i < n_check; i += blockDim.x) {
        if (ei32[2 * i + 1] != 0) { found = 1; break; }
    }
    if (found) atomicOr(&any, 1);
    __syncthreads();
    if (threadIdx.x == 0) *flag = any ? 0 : 1;
}

// ---------------------------------------------------------------------------
// Kernel B: h = x @ W1 + b1   (x: [N,27], W1: [27,64])
// 64 threads per node (thread t computes feature t), 4 nodes per block.
__global__ __launch_bounds__(256) void k_lin1(const float* __restrict__ x,
                                              const float* __restrict__ W1,
                                              const float* __restrict__ b1,
                                              float* __restrict__ h, int N) {
    __shared__ float Ws[27 * 64];
    __shared__ float bs[64];
    __shared__ float xs[4 * 27];
    int tid = threadIdx.x;
    for (int i = tid; i < 27 * 64; i += 256) Ws[i] = W1[i];
    if (tid < 64) bs[tid] = b1[tid];
    int base = blockIdx.x * 4;
    int xbase = base * 27;
    if (tid < 108) {
        int gidx = xbase + tid;
        xs[tid] = (gidx < N * 27) ? x[gidx] : 0.f;
    }
    __syncthreads();
    int g = tid >> 6, t = tid & 63;
    int node = base + g;
    if (node < N) {
        float acc = bs[t];
        const float* xr = &xs[g * 27];
#pragma unroll
        for (int k = 0; k < 27; ++k) acc = fmaf(xr[k], Ws[k * 64 + t], acc);
        h[(size_t)node * 64 + t] = acc;
    }
}

// ---------------------------------------------------------------------------
// Kernel C: agg[dst] += h[src] over all edges. 64 threads per edge.
__global__ __launch_bounds__(256) void k_scatter(const int* __restrict__ ei,
                                                 const float* __restrict__ h,
                                                 float* __restrict__ agg,
                                                 const int* __restrict__ flag,
                                                 int E) {
    int tid = threadIdx.x;
    int e = blockIdx.x * 4 + (tid >> 6);
    if (e >= E) return;
    int t = tid & 63;
    int mode = *flag;
    int src, dst;
    if (mode == 0) {            // int32 layout: [src x E][dst x E]
        src = ei[e];
        dst = ei[E + e];
    } else {                    // int64 layout: low words at even offsets
        src = ei[2 * e];
        dst = ei[2 * E + 2 * e];
    }
    float v = h[(size_t)src * 64 + t];
    atomicAdd(&agg[(size_t)dst * 64 + t], v);
}

// ---------------------------------------------------------------------------
// Kernel D: h2 = tanh(agg@Wrel + brel + h@Wroot); o = tanh(h2@W2 + b2);
//           loc/scale split + softplus + transpose write.
__global__ __launch_bounds__(256) void k_tail(const float* __restrict__ h,
                                              const float* __restrict__ agg,
                                              const float* __restrict__ Wrel,
                                              const float* __restrict__ brel,
                                              const float* __restrict__ Wroot,
                                              const float* __restrict__ W2,
                                              const float* __restrict__ b2,
                                              float* __restrict__ out, int N) {
    __shared__ float WrelS[64 * 64];
    __shared__ float WrootS[64 * 64];
    __shared__ float W2S[64 * 16];
    __shared__ float brelS[64];
    __shared__ float b2S[16];
    __shared__ float aggS[4 * 64];
    __shared__ float hS[4 * 64];
    __shared__ float h2S[4 * 64];
    int tid = threadIdx.x;
    for (int i = tid; i < 64 * 64; i += 256) {
        WrelS[i] = Wrel[i];
        WrootS[i] = Wroot[i];
    }
    for (int i = tid; i < 64 * 16; i += 256) W2S[i] = W2[i];
    if (tid < 64) brelS[tid] = brel[tid];
    if (tid < 16) b2S[tid] = b2[tid];
    int base = blockIdx.x * 4;
    size_t gload = (size_t)base * 64 + tid;   // 4 nodes * 64 feats == 256
    if (gload < (size_t)N * 64) {
        aggS[tid] = agg[gload];
        hS[tid] = h[gload];
    }
    __syncthreads();
    int g = tid >> 6, t = tid & 63;
    int node = base + g;
    if (node < N) {
        float acc = brelS[t];
        const float* ar = &aggS[g * 64];
        const float* hr = &hS[g * 64];
#pragma unroll 8
        for (int k = 0; k < 64; ++k) {
            acc = fmaf(ar[k], WrelS[k * 64 + t], acc);
            acc = fmaf(hr[k], WrootS[k * 64 + t], acc);
        }
        h2S[g * 64 + t] = tanhf(acc);
    }
    __syncthreads();
    if (node < N && t < 16) {
        float acc = b2S[t];
        const float* h2r = &h2S[g * 64];
#pragma unroll 8
        for (int k = 0; k < 64; ++k) acc = fmaf(h2r[k], W2S[k * 16 + t], acc);
        float o = tanhf(acc);
        if (t >= 8) {
            float sp = log1pf(expf(o + SP_BIAS));   // softplus, arg in (-0.5, 1.6)
            o = fmaxf(sp, 1e-4f);
        }
        out[(size_t)t * N + node] = o;
    }
}

// ---------------------------------------------------------------------------
extern "C" void kernel_launch(void* const* d_in, const int* in_sizes, int n_in,
                              void* d_out, int out_size, void* d_ws, size_t ws_size,
                              hipStream_t stream) {
    const float* x    = (const float*)d_in[0];
    const int*   ei   = (const int*)d_in[1];
    const float* W1   = (const float*)d_in[2];
    const float* b1   = (const float*)d_in[3];
    const float* Wrel = (const float*)d_in[4];
    const float* brel = (const float*)d_in[5];
    const float* Wroot= (const float*)d_in[6];
    const float* W2   = (const float*)d_in[7];
    const float* b2   = (const float*)d_in[8];

    int N = in_sizes[0] / 27;
    int E = in_sizes[1] / 2;

    float* h    = (float*)d_ws;
    float* agg  = h + (size_t)N * 64;
    int*   flag = (int*)(agg + (size_t)N * 64);

    hipMemsetAsync(agg, 0, (size_t)N * 64 * sizeof(float), stream);
    int ncheck = E < 65536 ? E : 65536;
    k_detect<<<1, 256, 0, stream>>>(ei, ncheck, flag);
    k_lin1<<<(N + 3) / 4, 256, 0, stream>>>(x, W1, b1, h, N);
    k_scatter<<<(E + 3) / 4, 256, 0, stream>>>(ei, h, agg, flag, E);
    k_tail<<<(N + 3) / 4, 256, 0, stream>>>(h, agg, Wrel, brel, Wroot, W2, b2,
                                            (float*)d_out, N);
}

// Round 2
// 470.052 us; speedup vs baseline: 1.1507x; 1.1507x over previous
//
#include <hip/hip_runtime.h>
#include <hip/hip_bf16.h>
#include <math.h>

static constexpr float SP_BIAS = 0.5413248546129181f; // log(expm1(1.0))

// ---------------------------------------------------------------------------
// Kernel: detect int32 vs int64 edge_index layout.
// If int64 (all values < 2^31), every odd int32 word is 0. flag=1 -> int64.
__global__ void k_detect(const int* __restrict__ ei32, int n_check,
                         int* __restrict__ flag) {
    __shared__ int any;
    if (threadIdx.x == 0) any = 0;
    __syncthreads();
    int found = 0;
    for (int i = threadIdx.x; i < n_check; i += blockDim.x) {
        if (ei32[2 * i + 1] != 0) { found = 1; break; }
    }
    if (found) atomicOr(&any, 1);
    __syncthreads();
    if (threadIdx.x == 0) *flag = any ? 0 : 1;
}

// ---------------------------------------------------------------------------
// h = x @ W1 + b1   (x: [N,27], W1: [27,64]); 64 threads/node, 4 nodes/block.
__global__ __launch_bounds__(256) void k_lin1(const float* __restrict__ x,
                                              const float* __restrict__ W1,
                                              const float* __restrict__ b1,
                                              float* __restrict__ h, int N) {
    __shared__ float Ws[27 * 64];
    __shared__ float bs[64];
    __shared__ float xs[4 * 27];
    int tid = threadIdx.x;
    for (int i = tid; i < 27 * 64; i += 256) Ws[i] = W1[i];
    if (tid < 64) bs[tid] = b1[tid];
    int base = blockIdx.x * 4;
    int xbase = base * 27;
    if (tid < 108) {
        int gidx = xbase + tid;
        xs[tid] = (gidx < N * 27) ? x[gidx] : 0.f;
    }
    __syncthreads();
    int g = tid >> 6, t = tid & 63;
    int node = base + g;
    if (node < N) {
        float acc = bs[t];
        const float* xr = &xs[g * 27];
#pragma unroll
        for (int k = 0; k < 27; ++k) acc = fmaf(xr[k], Ws[k * 64 + t], acc);
        h[(size_t)node * 64 + t] = acc;
    }
}

// ---------------------------------------------------------------------------
// deg[dst] += 1 over all edges (int atomics, 1 per edge).
__global__ __launch_bounds__(256) void k_hist(const int* __restrict__ ei,
                                              int* __restrict__ deg,
                                              const int* __restrict__ flag,
                                              int E) {
    int e = blockIdx.x * 256 + threadIdx.x;
    if (e >= E) return;
    int mode = *flag;
    int dst = (mode == 0) ? ei[E + e] : ei[2 * E + 2 * e];
    atomicAdd(&deg[dst], 1);
}

// ---------------------------------------------------------------------------
// Tile-wise exclusive scan: cursor[tile-local exclusive], blockSums[tile]=total
#define SCAN_TILE 1024
__global__ __launch_bounds__(256) void k_scan1(const int* __restrict__ deg,
                                               int* __restrict__ cursor,
                                               int* __restrict__ blockSums,
                                               int N) {
    __shared__ int sdata[256];
    int tid = threadIdx.x;
    int base = blockIdx.x * SCAN_TILE + tid * 4;
    int v[4];
#pragma unroll
    for (int j = 0; j < 4; ++j) {
        int idx = base + j;
        v[j] = (idx < N) ? deg[idx] : 0;
    }
    int tsum = v[0] + v[1] + v[2] + v[3];
    sdata[tid] = tsum;
    __syncthreads();
    // Hillis-Steele inclusive scan over 256 thread sums
    for (int off = 1; off < 256; off <<= 1) {
        int add = (tid >= off) ? sdata[tid - off] : 0;
        __syncthreads();
        sdata[tid] += add;
        __syncthreads();
    }
    int texcl = sdata[tid] - tsum;   // exclusive offset of this thread
    int run = texcl;
#pragma unroll
    for (int j = 0; j < 4; ++j) {
        int idx = base + j;
        if (idx < N) cursor[idx] = run;
        run += v[j];
    }
    if (tid == 255) blockSums[blockIdx.x] = sdata[255];
}

// Exclusive scan of blockSums (numTiles <= 256), single block.
__global__ __launch_bounds__(256) void k_scan2(int* __restrict__ blockSums,
                                               int numTiles) {
    __shared__ int sdata[256];
    int tid = threadIdx.x;
    int v = (tid < numTiles) ? blockSums[tid] : 0;
    sdata[tid] = v;
    __syncthreads();
    for (int off = 1; off < 256; off <<= 1) {
        int add = (tid >= off) ? sdata[tid - off] : 0;
        __syncthreads();
        sdata[tid] += add;
        __syncthreads();
    }
    if (tid < numTiles) blockSums[tid] = sdata[tid] - v;  // exclusive
}

__global__ __launch_bounds__(256) void k_scan3(int* __restrict__ cursor,
                                               const int* __restrict__ blockSums,
                                               int N) {
    int off = blockSums[blockIdx.x];
    int base = blockIdx.x * SCAN_TILE + threadIdx.x * 4;
#pragma unroll
    for (int j = 0; j < 4; ++j) {
        int idx = base + j;
        if (idx < N) cursor[idx] += off;
    }
}

// ---------------------------------------------------------------------------
// src_sorted[pos] = src, pos = cursor[dst]++ (after: cursor[n] == row end).
__global__ __launch_bounds__(256) void k_fill(const int* __restrict__ ei,
                                              int* __restrict__ cursor,
                                              int* __restrict__ src_sorted,
                                              const int* __restrict__ flag,
                                              int E) {
    int e = blockIdx.x * 256 + threadIdx.x;
    if (e >= E) return;
    int mode = *flag;
    int src, dst;
    if (mode == 0) { src = ei[e];      dst = ei[E + e]; }
    else           { src = ei[2 * e];  dst = ei[2 * E + 2 * e]; }
    int pos = atomicAdd(&cursor[dst], 1);
    src_sorted[pos] = src;
}

// ---------------------------------------------------------------------------
// Fused: agg = gather-sum(h[neighbors]); h2 = tanh(agg@Wrel+brel + h@Wroot);
// o = tanh(h2@W2+b2); split + softplus + transposed write.
// Persistent blocks: weights loaded into LDS once, grid-stride over chunks.
__global__ __launch_bounds__(256) void k_fused(const float* __restrict__ h,
                                               const int* __restrict__ src_sorted,
                                               const int* __restrict__ cursor,
                                               const int* __restrict__ deg,
                                               const float* __restrict__ Wrel,
                                               const float* __restrict__ brel,
                                               const float* __restrict__ Wroot,
                                               const float* __restrict__ W2,
                                               const float* __restrict__ b2,
                                               float* __restrict__ out,
                                               int N, int nchunks) {
    __shared__ float WrelS[64 * 64];
    __shared__ float WrootS[64 * 64];
    __shared__ float W2S[64 * 16];
    __shared__ float brelS[64];
    __shared__ float b2S[16];
    __shared__ float aggS[4 * 64];
    __shared__ float hS[4 * 64];
    __shared__ float h2S[4 * 64];
    int tid = threadIdx.x;
    for (int i = tid; i < 64 * 64; i += 256) {
        WrelS[i] = Wrel[i];
        WrootS[i] = Wroot[i];
    }
    for (int i = tid; i < 64 * 16; i += 256) W2S[i] = W2[i];
    if (tid < 64) brelS[tid] = brel[tid];
    if (tid < 16) b2S[tid] = b2[tid];
    __syncthreads();
    int g = tid >> 6, t = tid & 63;
    for (int chunk = blockIdx.x; chunk < nchunks; chunk += gridDim.x) {
        int node = chunk * 4 + g;
        float a = 0.f, hv = 0.f;
        if (node < N) {
            hv = h[(size_t)node * 64 + t];
            int end = cursor[node];
            int st = end - deg[node];
            int i = st;
            for (; i + 4 <= end; i += 4) {
                int s0 = src_sorted[i], s1 = src_sorted[i + 1];
                int s2 = src_sorted[i + 2], s3 = src_sorted[i + 3];
                float v0 = h[(size_t)s0 * 64 + t];
                float v1 = h[(size_t)s1 * 64 + t];
                float v2 = h[(size_t)s2 * 64 + t];
                float v3 = h[(size_t)s3 * 64 + t];
                a += v0 + v1 + v2 + v3;
            }
            for (; i < end; ++i) a += h[(size_t)src_sorted[i] * 64 + t];
        }
        aggS[g * 64 + t] = a;
        hS[g * 64 + t] = hv;
        __syncthreads();
        if (node < N) {
            float acc = brelS[t];
            const float* ar = &aggS[g * 64];
            const float* hr = &hS[g * 64];
#pragma unroll 8
            for (int k = 0; k < 64; ++k) {
                acc = fmaf(ar[k], WrelS[k * 64 + t], acc);
                acc = fmaf(hr[k], WrootS[k * 64 + t], acc);
            }
            h2S[g * 64 + t] = tanhf(acc);
        }
        __syncthreads();
        if (node < N && t < 16) {
            float acc = b2S[t];
            const float* h2r = &h2S[g * 64];
#pragma unroll 8
            for (int k = 0; k < 64; ++k) acc = fmaf(h2r[k], W2S[k * 16 + t], acc);
            float o = tanhf(acc);
            if (t >= 8) {
                float sp = log1pf(expf(o + SP_BIAS));
                o = fmaxf(sp, 1e-4f);
            }
            out[(size_t)t * N + node] = o;
        }
        __syncthreads();
    }
}

// ---------------------------------------------------------------------------
extern "C" void kernel_launch(void* const* d_in, const int* in_sizes, int n_in,
                              void* d_out, int out_size, void* d_ws, size_t ws_size,
                              hipStream_t stream) {
    const float* x    = (const float*)d_in[0];
    const int*   ei   = (const int*)d_in[1];
    const float* W1   = (const float*)d_in[2];
    const float* b1   = (const float*)d_in[3];
    const float* Wrel = (const float*)d_in[4];
    const float* brel = (const float*)d_in[5];
    const float* Wroot= (const float*)d_in[6];
    const float* W2   = (const float*)d_in[7];
    const float* b2   = (const float*)d_in[8];

    int N = in_sizes[0] / 27;
    int E = in_sizes[1] / 2;

    float* h          = (float*)d_ws;                       // N*64 f32
    int*   src_sorted = (int*)(h + (size_t)N * 64);         // E int
    int*   deg        = src_sorted + E;                     // N int
    int*   cursor     = deg + N;                            // N int
    int*   blockSums  = cursor + N;                         // 256 int
    int*   flag       = blockSums + 256;                    // 1 int

    int numTiles = (N + SCAN_TILE - 1) / SCAN_TILE;

    hipMemsetAsync(deg, 0, (size_t)N * sizeof(int), stream);
    int ncheck = 2 * E < 65536 ? 2 * E : 65536;
    k_detect<<<1, 256, 0, stream>>>(ei, ncheck, flag);
    k_lin1<<<(N + 3) / 4, 256, 0, stream>>>(x, W1, b1, h, N);
    k_hist<<<(E + 255) / 256, 256, 0, stream>>>(ei, deg, flag, E);
    k_scan1<<<numTiles, 256, 0, stream>>>(deg, cursor, blockSums, N);
    k_scan2<<<1, 256, 0, stream>>>(blockSums, numTiles);
    k_scan3<<<numTiles, 256, 0, stream>>>(cursor, blockSums, N);
    k_fill<<<(E + 255) / 256, 256, 0, stream>>>(ei, cursor, src_sorted, flag, E);
    int nchunks = (N + 3) / 4;
    int grid = nchunks < 1536 ? nchunks : 1536;
    k_fused<<<grid, 256, 0, stream>>>(h, src_sorted, cursor, deg, Wrel, brel,
                                      Wroot, W2, b2, (float*)d_out, N, nchunks);
}

// Round 3
// 340.465 us; speedup vs baseline: 1.5887x; 1.3806x over previous
//
#include <hip/hip_runtime.h>
#include <hip/hip_bf16.h>
#include <math.h>

typedef unsigned short ushort_t;
typedef float f32x4 __attribute__((ext_vector_type(4)));
typedef short bf16x8v __attribute__((ext_vector_type(8)));

static constexpr float SP_BIAS = 0.5413248546129181f; // log(expm1(1.0))

__device__ __forceinline__ ushort_t f2bf(float f) {
    union { float f; unsigned u; } v; v.f = f;
    unsigned r = v.u + 0x7FFFu + ((v.u >> 16) & 1u);   // RNE
    return (ushort_t)(r >> 16);
}
__device__ __forceinline__ float bf2f(ushort_t u) {
    union { unsigned u; float f; } v; v.u = ((unsigned)u) << 16;
    return v.f;
}

// ---------------------------------------------------------------------------
// Detect int32 vs int64 edge_index layout. is32 pre-zeroed; set to 1 if any
// odd int32 word nonzero (-> data is genuine int32 pairs, not int64 lows).
__global__ void k_detect(const int* __restrict__ ei32, int n_check,
                         int* __restrict__ is32) {
    int idx = blockIdx.x * 256 + threadIdx.x;
    int found = 0;
    for (int i = idx; i < n_check; i += 2048) {
        if (ei32[2 * i + 1] != 0) { found = 1; break; }
    }
    if (found) atomicOr(is32, 1);
}

// ---------------------------------------------------------------------------
// h_bf = bf16(x @ W1 + b1); 4 nodes/block, thread t of wave g -> feature t.
__global__ __launch_bounds__(256) void k_lin1(const float* __restrict__ x,
                                              const float* __restrict__ W1,
                                              const float* __restrict__ b1,
                                              ushort_t* __restrict__ h_bf, int N) {
    __shared__ float Ws[27 * 64];
    __shared__ float bs[64];
    __shared__ float xs[4 * 27];
    int tid = threadIdx.x;
    for (int i = tid; i < 27 * 64; i += 256) Ws[i] = W1[i];
    if (tid < 64) bs[tid] = b1[tid];
    int base = blockIdx.x * 4;
    if (tid < 108) {
        int gidx = base * 27 + tid;
        xs[tid] = (gidx < N * 27) ? x[gidx] : 0.f;
    }
    __syncthreads();
    int g = tid >> 6, t = tid & 63;
    int node = base + g;
    if (node < N) {
        float acc = bs[t];
        const float* xr = &xs[g * 27];
#pragma unroll
        for (int k = 0; k < 27; ++k) acc = fmaf(xr[k], Ws[k * 64 + t], acc);
        h_bf[(size_t)node * 64 + t] = f2bf(acc);
    }
}

// ---------------------------------------------------------------------------
// deg[dst] += 1 (1 int atomic per edge).
__global__ __launch_bounds__(256) void k_hist(const int* __restrict__ ei,
                                              int* __restrict__ deg,
                                              const int* __restrict__ is32,
                                              int E) {
    int e = blockIdx.x * 256 + threadIdx.x;
    if (e >= E) return;
    int dst = (*is32) ? ei[E + e] : ((const int2*)ei)[E + e].x;
    atomicAdd(&deg[dst], 1);
}

// ---------------------------------------------------------------------------
#define SCAN_TILE 1024
__global__ __launch_bounds__(256) void k_scan1(const int* __restrict__ deg,
                                               int* __restrict__ cursor,
                                               int* __restrict__ blockSums,
                                               int N) {
    __shared__ int sdata[256];
    int tid = threadIdx.x;
    int base = blockIdx.x * SCAN_TILE + tid * 4;
    int v[4];
#pragma unroll
    for (int j = 0; j < 4; ++j) {
        int idx = base + j;
        v[j] = (idx < N) ? deg[idx] : 0;
    }
    int tsum = v[0] + v[1] + v[2] + v[3];
    sdata[tid] = tsum;
    __syncthreads();
    for (int off = 1; off < 256; off <<= 1) {
        int add = (tid >= off) ? sdata[tid - off] : 0;
        __syncthreads();
        sdata[tid] += add;
        __syncthreads();
    }
    int run = sdata[tid] - tsum;
#pragma unroll
    for (int j = 0; j < 4; ++j) {
        int idx = base + j;
        if (idx < N) cursor[idx] = run;
        run += v[j];
    }
    if (tid == 255) blockSums[blockIdx.x] = sdata[255];
}

__global__ __launch_bounds__(256) void k_scan2(int* __restrict__ blockSums,
                                               int numTiles) {
    __shared__ int sdata[256];
    int tid = threadIdx.x;
    int v = (tid < numTiles) ? blockSums[tid] : 0;
    sdata[tid] = v;
    __syncthreads();
    for (int off = 1; off < 256; off <<= 1) {
        int add = (tid >= off) ? sdata[tid - off] : 0;
        __syncthreads();
        sdata[tid] += add;
        __syncthreads();
    }
    if (tid < numTiles) blockSums[tid] = sdata[tid] - v;
}

__global__ __launch_bounds__(256) void k_scan3(int* __restrict__ cursor,
                                               const int* __restrict__ blockSums,
                                               int N) {
    int off = blockSums[blockIdx.x];
    int base = blockIdx.x * SCAN_TILE + threadIdx.x * 4;
#pragma unroll
    for (int j = 0; j < 4; ++j) {
        int idx = base + j;
        if (idx < N) cursor[idx] += off;
    }
}

// ---------------------------------------------------------------------------
// src_sorted[cursor[dst]++] = src. After: cursor[n] == row end of n.
__global__ __launch_bounds__(256) void k_fill(const int* __restrict__ ei,
                                              int* __restrict__ cursor,
                                              int* __restrict__ src_sorted,
                                              const int* __restrict__ is32,
                                              int E) {
    int e = blockIdx.x * 256 + threadIdx.x;
    if (e >= E) return;
    int src, dst;
    if (*is32) { src = ei[e]; dst = ei[E + e]; }
    else { src = ((const int2*)ei)[e].x; dst = ((const int2*)ei)[E + e].x; }
    int pos = atomicAdd(&cursor[dst], 1);
    src_sorted[pos] = src;
}

// ---------------------------------------------------------------------------
// agg_bf[n] = bf16( sum_{s in row n} h_bf[s] ). One wave per node, lane t =
// feature t. No LDS, no barriers; 8-deep unrolled independent loads for MLP.
__global__ __launch_bounds__(256) void k_agg(const ushort_t* __restrict__ h_bf,
                                             const int* __restrict__ src_sorted,
                                             const int* __restrict__ rowend,
                                             const int* __restrict__ deg,
                                             ushort_t* __restrict__ agg_bf, int N) {
    int w = (blockIdx.x * 256 + threadIdx.x) >> 6;
    int t = threadIdx.x & 63;
    if (w >= N) return;
    int end = rowend[w];
    int i = end - deg[w];
    float a = 0.f;
    for (; i + 8 <= end; i += 8) {
        int s0 = src_sorted[i],     s1 = src_sorted[i + 1];
        int s2 = src_sorted[i + 2], s3 = src_sorted[i + 3];
        int s4 = src_sorted[i + 4], s5 = src_sorted[i + 5];
        int s6 = src_sorted[i + 6], s7 = src_sorted[i + 7];
        float v0 = bf2f(h_bf[(size_t)s0 * 64 + t]);
        float v1 = bf2f(h_bf[(size_t)s1 * 64 + t]);
        float v2 = bf2f(h_bf[(size_t)s2 * 64 + t]);
        float v3 = bf2f(h_bf[(size_t)s3 * 64 + t]);
        float v4 = bf2f(h_bf[(size_t)s4 * 64 + t]);
        float v5 = bf2f(h_bf[(size_t)s5 * 64 + t]);
        float v6 = bf2f(h_bf[(size_t)s6 * 64 + t]);
        float v7 = bf2f(h_bf[(size_t)s7 * 64 + t]);
        a += ((v0 + v1) + (v2 + v3)) + ((v4 + v5) + (v6 + v7));
    }
    for (; i < end; ++i) a += bf2f(h_bf[(size_t)src_sorted[i] * 64 + t]);
    agg_bf[(size_t)w * 64 + t] = f2bf(a);
}

// ---------------------------------------------------------------------------
// MFMA tail: h2 = tanh(agg@Wrel + brel + h@Wroot); o = tanh(h2@W2 + b2);
// split + softplus + transposed store. One wave per 16-node tile.
// A-frag (16x16x32): lane l holds A[l&15][8*(l>>4)+j], j=0..7 contiguous bf16.
// B-frag: lane l holds B[8*(l>>4)+j][l&15] -> pre-packed per (kt,nt) in LDS.
// C/D: col=lane&15, row=(lane>>4)*4+reg (measured layout).
__global__ __launch_bounds__(256) void k_tail(const ushort_t* __restrict__ h_bf,
                                              const ushort_t* __restrict__ agg_bf,
                                              const float* __restrict__ Wrel,
                                              const float* __restrict__ brel,
                                              const float* __restrict__ Wroot,
                                              const float* __restrict__ W2,
                                              const float* __restrict__ b2,
                                              float* __restrict__ out,
                                              int N, int ntiles) {
    __shared__ alignas(16) ushort_t WrelF[8 * 512];   // (kt*4+nt)*512 + lane*8 + j
    __shared__ alignas(16) ushort_t WrootF[8 * 512];
    __shared__ alignas(16) ushort_t W2F[2 * 512];     // kt*512 + lane*8 + j
    __shared__ alignas(16) ushort_t h2T[4][16 * 72];  // per-wave, row stride 72
    __shared__ float brelS[64];
    __shared__ float b2S[16];
    int tid = threadIdx.x;
    for (int i = tid; i < 4096; i += 256) {
        int j = i & 7, lane = (i >> 3) & 63, grp = i >> 9;
        int kt = grp >> 2, nt = grp & 3;
        int k = (kt << 5) + ((lane >> 4) << 3) + j;
        int n = (nt << 4) + (lane & 15);
        WrelF[i]  = f2bf(Wrel[k * 64 + n]);
        WrootF[i] = f2bf(Wroot[k * 64 + n]);
    }
    for (int i = tid; i < 1024; i += 256) {
        int j = i & 7, lane = (i >> 3) & 63, kt = i >> 9;
        int k = (kt << 5) + ((lane >> 4) << 3) + j;
        int n = (lane & 15);
        W2F[i] = f2bf(W2[k * 16 + n]);
    }
    if (tid < 64) brelS[tid] = brel[tid];
    if (tid < 16) b2S[tid] = b2[tid];
    __syncthreads();

    int lane = tid & 63;
    int wv = tid >> 6;
    int lrow = lane & 15;       // A-row / C-col within tile
    int lkg = lane >> 4;        // 0..3
    const bf16x8v* WrelV  = (const bf16x8v*)WrelF;
    const bf16x8v* WrootV = (const bf16x8v*)WrootF;
    const bf16x8v* W2V    = (const bf16x8v*)W2F;
    ushort_t* myT = h2T[wv];

    int tile = blockIdx.x * 4 + wv;
    if (tile >= ntiles) return;
    int rbase = tile * 16;
    int arow = rbase + lrow; if (arow >= N) arow = N - 1;
    const bf16x8v* aggV = (const bf16x8v*)(agg_bf + (size_t)arow * 64);
    const bf16x8v* hV   = (const bf16x8v*)(h_bf + (size_t)arow * 64);
    bf16x8v a0 = aggV[lkg], a1 = aggV[4 + lkg];
    bf16x8v x0 = hV[lkg],   x1 = hV[4 + lkg];

    f32x4 acc[4];
#pragma unroll
    for (int nt = 0; nt < 4; ++nt) { acc[nt] = (f32x4){0.f, 0.f, 0.f, 0.f}; }
#pragma unroll
    for (int nt = 0; nt < 4; ++nt) {
        acc[nt] = __builtin_amdgcn_mfma_f32_16x16x32_bf16(a0, WrelV[(0 * 4 + nt) * 64 + lane], acc[nt], 0, 0, 0);
        acc[nt] = __builtin_amdgcn_mfma_f32_16x16x32_bf16(a1, WrelV[(1 * 4 + nt) * 64 + lane], acc[nt], 0, 0, 0);
        acc[nt] = __builtin_amdgcn_mfma_f32_16x16x32_bf16(x0, WrootV[(0 * 4 + nt) * 64 + lane], acc[nt], 0, 0, 0);
        acc[nt] = __builtin_amdgcn_mfma_f32_16x16x32_bf16(x1, WrootV[(1 * 4 + nt) * 64 + lane], acc[nt], 0, 0, 0);
    }
    // h2 tile -> tanh -> per-wave LDS transpose (node-major rows for GEMM2 A)
#pragma unroll
    for (int nt = 0; nt < 4; ++nt) {
        int feat = nt * 16 + lrow;
        float bias = brelS[feat];
#pragma unroll
        for (int r = 0; r < 4; ++r) {
            int noderow = lkg * 4 + r;
            myT[noderow * 72 + feat] = f2bf(tanhf(acc[nt][r] + bias));
        }
    }
    __threadfence_block();  // order LDS writes before cross-lane reads (same wave)
    const bf16x8v* h2V = (const bf16x8v*)myT;
    bf16x8v p0 = h2V[lrow * 9 + lkg];
    bf16x8v p1 = h2V[lrow * 9 + 4 + lkg];
    f32x4 acc2 = (f32x4){0.f, 0.f, 0.f, 0.f};
    acc2 = __builtin_amdgcn_mfma_f32_16x16x32_bf16(p0, W2V[0 * 64 + lane], acc2, 0, 0, 0);
    acc2 = __builtin_amdgcn_mfma_f32_16x16x32_bf16(p1, W2V[1 * 64 + lane], acc2, 0, 0, 0);

    int feat = lrow;  // 0..15: 0-7 loc, 8-15 scale
    float bias2 = b2S[feat];
#pragma unroll
    for (int r = 0; r < 4; ++r) {
        int node = rbase + lkg * 4 + r;
        float o = tanhf(acc2[r] + bias2);
        if (feat >= 8) {
            float sp = log1pf(expf(o + SP_BIAS));
            o = fmaxf(sp, 1e-4f);
        }
        if (node < N) out[(size_t)feat * N + node] = o;
    }
}

// ---------------------------------------------------------------------------
extern "C" void kernel_launch(void* const* d_in, const int* in_sizes, int n_in,
                              void* d_out, int out_size, void* d_ws, size_t ws_size,
                              hipStream_t stream) {
    const float* x    = (const float*)d_in[0];
    const int*   ei   = (const int*)d_in[1];
    const float* W1   = (const float*)d_in[2];
    const float* b1   = (const float*)d_in[3];
    const float* Wrel = (const float*)d_in[4];
    const float* brel = (const float*)d_in[5];
    const float* Wroot= (const float*)d_in[6];
    const float* W2   = (const float*)d_in[7];
    const float* b2   = (const float*)d_in[8];

    int N = in_sizes[0] / 27;
    int E = in_sizes[1] / 2;

    ushort_t* h_bf       = (ushort_t*)d_ws;                 // N*64 bf16
    ushort_t* agg_bf     = h_bf + (size_t)N * 64;           // N*64 bf16
    int*      src_sorted = (int*)(agg_bf + (size_t)N * 64); // E int
    int*      deg        = src_sorted + E;                  // N int
    int*      cursor     = deg + N;                         // N int
    int*      blockSums  = cursor + N;                      // 256 int
    int*      is32       = blockSums + 256;                 // 1 int

    int numTiles = (N + SCAN_TILE - 1) / SCAN_TILE;
    int ntiles16 = (N + 15) / 16;

    // zero deg .. is32 in one shot (cursor overwritten by scan anyway)
    hipMemsetAsync(deg, 0, (size_t)(2 * N + 257) * sizeof(int), stream);
    int ncheck = 2 * E < 65536 ? 2 * E : 65536;
    k_detect<<<8, 256, 0, stream>>>(ei, ncheck, is32);
    k_lin1<<<(N + 3) / 4, 256, 0, stream>>>(x, W1, b1, h_bf, N);
    k_hist<<<(E + 255) / 256, 256, 0, stream>>>(ei, deg, is32, E);
    k_scan1<<<numTiles, 256, 0, stream>>>(deg, cursor, blockSums, N);
    k_scan2<<<1, 256, 0, stream>>>(blockSums, numTiles);
    k_scan3<<<numTiles, 256, 0, stream>>>(cursor, blockSums, N);
    k_fill<<<(E + 255) / 256, 256, 0, stream>>>(ei, cursor, src_sorted, is32, E);
    k_agg<<<(N + 3) / 4, 256, 0, stream>>>(h_bf, src_sorted, cursor, deg, agg_bf, N);
    k_tail<<<(ntiles16 + 3) / 4, 256, 0, stream>>>(h_bf, agg_bf, Wrel, brel, Wroot,
                                                   W2, b2, (float*)d_out, N, ntiles16);
}